// Round 1
// baseline (2473.604 us; speedup 1.0000x reference)
//
#include <hip/hip_runtime.h>

// VanillaRNN: h_{t+1} = tanh(W_hx x_t + W_hh h_t + b_h), T=1024, H=512, B=256.
// R14: run the 512x512 GEMV on BOTH per-CU issue pipes (m114: MFMA pipe and
// VALU pipe co-schedule, time ~= max not sum). R13 was VALU-issue-bound
// (VALUBusy 80%, MfmaUtil 0, dot2 floor 2048 cy/step).
//   waves 0..3 (VALU gang): rows 0..255 via v_dot2_f32_f16 k-slice partials
//     (R9 structure, halved: wave w owns k in [128w,128w+128), 4 rows/lane,
//     pairs 0..55 in regs (224 -> acc file via pins), pairs 56..63 in LDS).
//   waves 4..7 (MFMA gang): rows 256..511 via v_mfma_f32_16x16x32_f16,
//     4 16-row tiles/wave, full-k accumulation in regs (NO partial reduce).
//     B operand = h replicated to all 16 cols (B n-layout irrelevant; every
//     lane's D copy valid). A and B packed with the identical
//     (lane>>4, elem)->k function so any HW k-permutation cancels. D read
//     via m89-verified C/D layout: col=lane&15, row=(lane>>4)*4+reg.
//     A-frags: ksteps 0..13 in regs (224 words, acc-file budget), 14..15 in
//     LDS (32 KB) to stay under the ~256/wave acc cap at 2 waves/EU.
// Two s_barriers/step: b1 = partials + MFMA-h visible (MFMA rows publish
// pre-b1, they need no reduce), b2 = VALU-h visible. Double-buffered hs.
// Budget/SIMD/step: VALU wave ~1150 cy (256 dot2@4cy + 64 readlane) ||
// MFMA wave ~1242 cy (64 mfma @ ~19.4 cy) + reduce/barrier tail ~400
// => ~1700-2100 cy/step vs R13's 3370.

#define T_SEQ    1024
#define HID      512
#define NTHREADS 512
#define NW       8
#define NCLS     10

// VALU gang
#define RV       256          // rows 0..255
#define RPV      4            // rows per lane
#define PREG_V   56           // pairs 0..55 in regs
#define PSTRIDE  288          // padded partial row: 256 + pad

// MFMA gang
#define NTILE    4            // 16-row tiles per MFMA wave
#define KSTEPS   16           // 512 / 32
#define KREG     14           // ksteps 0..13 in regs, 14..15 in LDS

typedef _Float16 half2_t __attribute__((ext_vector_type(2)));
typedef _Float16 half8_t __attribute__((ext_vector_type(8)));
typedef float    f32x4_t __attribute__((ext_vector_type(4)));

#if __has_builtin(__builtin_amdgcn_sched_barrier)
#define SCHED_BARRIER() __builtin_amdgcn_sched_barrier(0)
#else
#define SCHED_BARRIER()
#endif

__device__ __forceinline__ unsigned int pack2(float a, float b) {
    half2_t h = {(_Float16)a, (_Float16)b};
    return __builtin_bit_cast(unsigned int, h);
}

__device__ __forceinline__ float dot2(unsigned int w, unsigned int h, float acc) {
#if __has_builtin(__builtin_amdgcn_fdot2)
    return __builtin_amdgcn_fdot2(__builtin_bit_cast(half2_t, w),
                                  __builtin_bit_cast(half2_t, h), acc, false);
#else
    half2_t wv = __builtin_bit_cast(half2_t, w), hv = __builtin_bit_cast(half2_t, h);
    return acc + (float)wv.x * (float)hv.x + (float)wv.y * (float)hv.y;
#endif
}

__device__ __forceinline__ unsigned int bcast(unsigned int v, int lane) {
#if __has_builtin(__builtin_amdgcn_readlane)
    return __builtin_amdgcn_readlane(v, lane);   // -> SGPR, uniform
#else
    return __shfl((int)v, lane, 64);
#endif
}

// Bank-balanced padded index (multiple-of-4 pad keeps 16 B alignment).
__device__ __forceinline__ int pidx(int row) { return row + ((row >> 5) << 2); }

__device__ __forceinline__ float fast_tanh(float s) {
    // tanh(s) = 1 - 2/(e^{2s}+1); exp2(s*2*log2e). Exact at +/-inf.
#if __has_builtin(__builtin_amdgcn_exp2f)
    float e = __builtin_amdgcn_exp2f(s * 2.885390081777927f);
#else
    float e = __expf(2.0f * s);
#endif
    return 1.0f - 2.0f / (e + 1.0f);
}

// Raw barrier with explicit LDS drain (used inside wave-uniform branches;
// both gangs execute an identical barrier count per iteration).
__device__ __forceinline__ void wg_barrier() {
    asm volatile("s_waitcnt lgkmcnt(0)" ::: "memory");
    __builtin_amdgcn_s_barrier();
    asm volatile("" ::: "memory");
}

__global__ __attribute__((amdgpu_flat_work_group_size(NTHREADS, NTHREADS)))
           __attribute__((amdgpu_waves_per_eu(2, 2)))
void rnn_persist(
    const float* __restrict__ x, const float* __restrict__ h_init,
    const float* __restrict__ W_hx, const float* __restrict__ W_hh,
    const float* __restrict__ b_h, const float* __restrict__ W_ph,
    const float* __restrict__ b_p, float* __restrict__ out)
{
    __shared__ __align__(16) float    x_s[T_SEQ];        //  4 KB
    __shared__ __align__(16) float    part[4][PSTRIDE];  //  4.5 KB (single-buf: b2 fences reuse)
    __shared__ __align__(16) _Float16 hs[2][HID];        //  2 KB: h, double-buffered
    __shared__ uint4 WlA[4][RPV][64];                    // 16 KB: VALU pairs 56..59
    __shared__ uint4 WlB[4][RPV][64];                    // 16 KB: VALU pairs 60..63
    __shared__ uint4 Aspill[4][NTILE][2][64];            // 32 KB: MFMA A ksteps 14,15

    const int tid  = threadIdx.x;
    const int b    = blockIdx.x;
    const int w    = tid >> 6;
    const int lane = tid & 63;

    for (int i = tid; i < T_SEQ; i += NTHREADS) x_s[i] = x[(size_t)b * T_SEQ + i];
    hs[0][tid] = (_Float16)h_init[tid];

    if (w < 4) {
        // ================= VALU gang: rows 0..255 =================
        const float whx = W_hx[tid];          // reduce phase: thread owns row tid
        const float bh  = b_h[tid];
        const int   pi  = pidx(tid);

        unsigned int wreg[RPV][PREG_V];       // 224 words (acc file via pins)
        #pragma unroll
        for (int r = 0; r < RPV; ++r) {
            const float* row = W_hh + (size_t)(RPV * lane + r) * HID + 128 * w;
            #pragma unroll
            for (int q = 0; q < 14; ++q) {    // pairs 0..27
                float4 v = *(const float4*)(row + 4 * q);
                wreg[r][2 * q]     = pack2(v.x, v.y);
                wreg[r][2 * q + 1] = pack2(v.z, v.w);
            }
            SCHED_BARRIER();
            #pragma unroll
            for (int q = 14; q < 28; ++q) {   // pairs 28..55
                float4 v = *(const float4*)(row + 4 * q);
                wreg[r][2 * q]     = pack2(v.x, v.y);
                wreg[r][2 * q + 1] = pack2(v.z, v.w);
            }
            // pairs 56..63 -> LDS (two conflict-free lane-major arrays)
            float4 a0 = *(const float4*)(row + 112);
            float4 a1 = *(const float4*)(row + 116);
            WlA[w][r][lane] = make_uint4(pack2(a0.x, a0.y), pack2(a0.z, a0.w),
                                         pack2(a1.x, a1.y), pack2(a1.z, a1.w));
            float4 b0 = *(const float4*)(row + 120);
            float4 b1 = *(const float4*)(row + 124);
            WlB[w][r][lane] = make_uint4(pack2(b0.x, b0.y), pack2(b0.z, b0.w),
                                         pack2(b1.x, b1.y), pack2(b1.z, b1.w));
            SCHED_BARRIER();                  // keep init-phase pressure low
        }
        // Opaque identity pin: blocks rematerialization of the packed W values.
        #pragma unroll
        for (int r = 0; r < RPV; ++r)
            #pragma unroll
            for (int p = 0; p < PREG_V; ++p)
                asm volatile("" : "+v"(wreg[r][p]));

        wg_barrier();                         // pre-loop sync (matches MFMA gang)

        float hval = 0.0f;
        #pragma unroll 1
        for (int t = 0; t < T_SEQ; ++t) {
            const int cur = t & 1;
            const float xw = x_s[t];
            // lane p holds h pair p of this wave's 128-wide k-slice
            unsigned int hpack = ((const unsigned int*)hs[cur])[64 * w + lane];

            float acc[RPV] = {0.0f, 0.0f, 0.0f, 0.0f};
            #pragma unroll
            for (int p = 0; p < PREG_V; ++p) {
                unsigned int hp = bcast(hpack, p);
                #pragma unroll
                for (int r = 0; r < RPV; ++r) acc[r] = dot2(wreg[r][p], hp, acc[r]);
            }
            {   // pairs 56..63 from LDS, one b128 per row per array
                unsigned int h0 = bcast(hpack, 56), h1 = bcast(hpack, 57),
                             h2 = bcast(hpack, 58), h3 = bcast(hpack, 59);
                #pragma unroll
                for (int r = 0; r < RPV; ++r) {
                    uint4 q = WlA[w][r][lane];
                    acc[r] = dot2(q.x, h0, acc[r]);
                    acc[r] = dot2(q.y, h1, acc[r]);
                    acc[r] = dot2(q.z, h2, acc[r]);
                    acc[r] = dot2(q.w, h3, acc[r]);
                }
                h0 = bcast(hpack, 60); h1 = bcast(hpack, 61);
                h2 = bcast(hpack, 62); h3 = bcast(hpack, 63);
                #pragma unroll
                for (int r = 0; r < RPV; ++r) {
                    uint4 q = WlB[w][r][lane];
                    acc[r] = dot2(q.x, h0, acc[r]);
                    acc[r] = dot2(q.y, h1, acc[r]);
                    acc[r] = dot2(q.z, h2, acc[r]);
                    acc[r] = dot2(q.w, h3, acc[r]);
                }
            }
            // partials for rows 4*lane..4*lane+3, swizzled b128
            *(float4*)&part[w][pidx(RPV * lane)] =
                make_float4(acc[0], acc[1], acc[2], acc[3]);

            wg_barrier();   // b1: partials + MFMA-row h visible

            float s = whx * xw + bh;
            #pragma unroll
            for (int j = 0; j < 4; ++j) s += part[j][pi];
            hval = fast_tanh(s);
            hs[cur ^ 1][tid] = (_Float16)hval;

            wg_barrier();   // b2: VALU-row h visible
        }
        x_s[tid] = hval;    // stage final f32 h, rows 0..255
    } else {
        // ================= MFMA gang: rows 256..511 =================
        const int widx  = w - 4;
        const int g     = lane >> 4;          // k-group (0..3)
        const int rloc  = lane & 15;          // row within 16-row tile
        const int rbase = RV + 64 * widx;     // 256, 320, 384, 448

        half8_t afrag[NTILE][KREG];           // 224 words (acc file)
        float   whxr[NTILE][4], bhr[NTILE][4];
        #pragma unroll
        for (int tt = 0; tt < NTILE; ++tt) {
            const float* rowp = W_hh + (size_t)(rbase + 16 * tt + rloc) * HID;
            #pragma unroll
            for (int ks = 0; ks < KREG; ++ks) {
                float4 v0 = *(const float4*)(rowp + 32 * ks + 8 * g);
                float4 v1 = *(const float4*)(rowp + 32 * ks + 8 * g + 4);
                half8_t a = {(_Float16)v0.x, (_Float16)v0.y, (_Float16)v0.z, (_Float16)v0.w,
                             (_Float16)v1.x, (_Float16)v1.y, (_Float16)v1.z, (_Float16)v1.w};
                afrag[tt][ks] = a;
                if (ks == 6) SCHED_BARRIER();
            }
            SCHED_BARRIER();
            #pragma unroll
            for (int ks = KREG; ks < KSTEPS; ++ks) {   // ksteps 14,15 -> LDS
                float4 v0 = *(const float4*)(rowp + 32 * ks + 8 * g);
                float4 v1 = *(const float4*)(rowp + 32 * ks + 8 * g + 4);
                Aspill[widx][tt][ks - KREG][lane] =
                    make_uint4(pack2(v0.x, v0.y), pack2(v0.z, v0.w),
                               pack2(v1.x, v1.y), pack2(v1.z, v1.w));
            }
            #pragma unroll
            for (int qq = 0; qq < 4; ++qq) {  // D row = 4*g + qq within tile (m89)
                const int rr = rbase + 16 * tt + 4 * g + qq;
                whxr[tt][qq] = W_hx[rr];
                bhr[tt][qq]  = b_h[rr];
            }
            SCHED_BARRIER();
        }

        f32x4_t acc[NTILE];
        wg_barrier();                         // pre-loop sync (matches VALU gang)

        #pragma unroll 1
        for (int t = 0; t < T_SEQ; ++t) {
            const int cur = t & 1;
            #pragma unroll
            for (int tt = 0; tt < NTILE; ++tt) acc[tt] = (f32x4_t){0.f, 0.f, 0.f, 0.f};

            #pragma unroll
            for (int ks = 0; ks < KREG; ++ks) {
                // B = h replicated to all 16 cols: every lane loads its
                // k-range h[32ks+8g .. +8) (16-lane broadcast, conflict-free)
                half8_t bf = *(const half8_t*)&hs[cur][32 * ks + 8 * g];
                #pragma unroll
                for (int tt = 0; tt < NTILE; ++tt)
                    acc[tt] = __builtin_amdgcn_mfma_f32_16x16x32_f16(
                                  afrag[tt][ks], bf, acc[tt], 0, 0, 0);
            }
            #pragma unroll
            for (int ks = KREG; ks < KSTEPS; ++ks) {
                half8_t bf = *(const half8_t*)&hs[cur][32 * ks + 8 * g];
                #pragma unroll
                for (int tt = 0; tt < NTILE; ++tt) {
                    half8_t a = __builtin_bit_cast(half8_t,
                                    Aspill[widx][tt][ks - KREG][lane]);
                    acc[tt] = __builtin_amdgcn_mfma_f32_16x16x32_f16(
                                  a, bf, acc[tt], 0, 0, 0);
                }
            }

            // rows 256..511 are final (full-k in-register): tanh + publish
            // pre-b1. Writer lanes: col 0 of each 16-lane group.
            const float xw = x_s[t];
            if (rloc == 0) {
                #pragma unroll
                for (int tt = 0; tt < NTILE; ++tt) {
                    float v0 = fast_tanh(acc[tt][0] + whxr[tt][0] * xw + bhr[tt][0]);
                    float v1 = fast_tanh(acc[tt][1] + whxr[tt][1] * xw + bhr[tt][1]);
                    float v2 = fast_tanh(acc[tt][2] + whxr[tt][2] * xw + bhr[tt][2]);
                    float v3 = fast_tanh(acc[tt][3] + whxr[tt][3] * xw + bhr[tt][3]);
                    *(uint2*)&hs[cur ^ 1][rbase + 16 * tt + 4 * g] =
                        make_uint2(pack2(v0, v1), pack2(v2, v3));
                }
            }

            wg_barrier();   // b1
            wg_barrier();   // b2
        }

        // stage final f32 h, rows 256..511 (acc still holds last step's sums)
        const float xwl = x_s[T_SEQ - 1];
        if (rloc == 0) {
            #pragma unroll
            for (int tt = 0; tt < NTILE; ++tt) {
                float v0 = fast_tanh(acc[tt][0] + whxr[tt][0] * xwl + bhr[tt][0]);
                float v1 = fast_tanh(acc[tt][1] + whxr[tt][1] * xwl + bhr[tt][1]);
                float v2 = fast_tanh(acc[tt][2] + whxr[tt][2] * xwl + bhr[tt][2]);
                float v3 = fast_tanh(acc[tt][3] + whxr[tt][3] * xwl + bhr[tt][3]);
                *(float4*)&x_s[rbase + 16 * tt + 4 * g] =
                    make_float4(v0, v1, v2, v3);
            }
        }
    }

    // Epilogue: p = W_ph @ h_last + b_p (h_last f32 staged in x_s[0..512))
    __syncthreads();

    for (int c = w; c < NCLS; c += NW) {
        float s = 0.0f;
        #pragma unroll
        for (int j = 0; j < 8; ++j) {
            int r = lane + 64 * j;
            s += W_ph[c * HID + r] * x_s[r];
        }
        #pragma unroll
        for (int off = 32; off; off >>= 1) s += __shfl_down(s, off, 64);
        if (lane == 0) out[b * NCLS + c] = s + b_p[c];
    }
}

extern "C" void kernel_launch(void* const* d_in, const int* in_sizes, int n_in,
                              void* d_out, int out_size, void* d_ws, size_t ws_size,
                              hipStream_t stream) {
    const float* x      = (const float*)d_in[0];
    const float* h_init = (const float*)d_in[1];
    const float* W_hx   = (const float*)d_in[2];
    const float* W_hh   = (const float*)d_in[3];
    const float* b_h    = (const float*)d_in[4];
    const float* W_ph   = (const float*)d_in[5];
    const float* b_p    = (const float*)d_in[6];
    float* out = (float*)d_out;

    const int B = in_sizes[0] / T_SEQ;   // 256 batch columns -> 256 workgroups
    rnn_persist<<<B, NTHREADS, 0, stream>>>(x, h_init, W_hx, W_hh, b_h, W_ph, b_p, out);
}